// Round 1
// baseline (496.697 us; speedup 1.0000x reference)
//
#include <hip/hip_runtime.h>
#include <hip/hip_bf16.h>

using bf16 = __hip_bfloat16;
typedef __bf16 bf16x8 __attribute__((ext_vector_type(8)));
typedef float f32x4 __attribute__((ext_vector_type(4)));

#define AS1(p) ((const __attribute__((address_space(1))) void*)(p))
#define AS3(p) ((__attribute__((address_space(3))) void*)(p))

// ---------------------------------------------------------------------------
// Kernel 1: fold the separable FIR into the conv weights.
// Wsub[ph][jy*3+jx][oc][ic], ic contiguous (bf16) so B-tiles stage like A.
// Ay[py][jy][p] = fr[p + (2+py) - 2*jy],  fr = [.25,.75,.75,.25]
// ---------------------------------------------------------------------------
__global__ void prep_wsub_k(const float* __restrict__ w, bf16* __restrict__ wsub) {
  const int o = blockIdx.x, i = threadIdx.x;
  const float* wp = w + (size_t)(o * 256 + i) * 9;
  float wv[9];
#pragma unroll
  for (int p = 0; p < 9; ++p) wv[p] = wp[p];
  const float A[2][3][3] = {
      {{0.75f, 0.25f, 0.00f}, {0.25f, 0.75f, 0.75f}, {0.00f, 0.00f, 0.25f}},
      {{0.25f, 0.00f, 0.00f}, {0.75f, 0.75f, 0.25f}, {0.00f, 0.25f, 0.75f}}};
#pragma unroll
  for (int py = 0; py < 2; ++py)
#pragma unroll
    for (int px = 0; px < 2; ++px) {
      const int ph = py * 2 + px;
#pragma unroll
      for (int jy = 0; jy < 3; ++jy)
#pragma unroll
        for (int jx = 0; jx < 3; ++jx) {
          float s = 0.f;
#pragma unroll
          for (int p = 0; p < 3; ++p)
#pragma unroll
            for (int q = 0; q < 3; ++q)
              s += wv[p * 3 + q] * A[py][jy][p] * A[px][jx][q];
          wsub[((size_t)((ph * 9 + jy * 3 + jx) * 256 + o)) * 256 + i] =
              __float2bfloat16(s);
        }
    }
}

// ---------------------------------------------------------------------------
// Kernel 2: x NCHW fp32 -> padded NHWC bf16 [16][66][66][256] (border = 0,
// pre-zeroed by memset). LDS transpose per (n, iy, 64-ic block).
// ---------------------------------------------------------------------------
__global__ void xpose_k(const float* __restrict__ x, bf16* __restrict__ xpad) {
  const int b = blockIdx.x;
  const int icb = b & 3, iy = (b >> 2) & 63, n = b >> 8;
  __shared__ bf16 lds[64][72];  // [ix][c]
  const int t = threadIdx.x;
  const int c = t & 63, ixg = t >> 6;
  const float* src = x + (((size_t)(n * 256 + icb * 64 + c) * 64 + iy) * 64);
#pragma unroll
  for (int rep = 0; rep < 4; ++rep) {
    const int ix0 = ixg * 16 + rep * 4;
    float4 v = *reinterpret_cast<const float4*>(src + ix0);
    lds[ix0 + 0][c] = __float2bfloat16(v.x);
    lds[ix0 + 1][c] = __float2bfloat16(v.y);
    lds[ix0 + 2][c] = __float2bfloat16(v.z);
    lds[ix0 + 3][c] = __float2bfloat16(v.w);
  }
  __syncthreads();
  const int ix = t >> 2, cseg = (t & 3) * 16;
  bf16* dst = xpad + (((size_t)(n * 66 + iy + 1) * 66 + ix + 1) * 256 + icb * 64 + cseg);
  typedef short short8 __attribute__((ext_vector_type(8)));
  *reinterpret_cast<short8*>(dst) = *reinterpret_cast<const short8*>(&lds[ix][cseg]);
  *reinterpret_cast<short8*>(dst + 8) = *reinterpret_cast<const short8*>(&lds[ix][cseg + 8]);
}

// ---------------------------------------------------------------------------
// Kernel 3: fused conv as MFMA GEMM. Per block: one phase, 128 oc x 128 m,
// K = 9 taps x 256 ic. m97 structure: global_load_lds(16B) staging with
// pre-swizzled source, XOR-swizzled ds_read_b128, single LDS buffer.
// Operands: A = Wsub rows (oc), B = x rows (m) -> C row=oc, col=m.
// ---------------------------------------------------------------------------
__global__ void conv_k(const bf16* __restrict__ xpad, const bf16* __restrict__ wsub,
                       const float* __restrict__ bias, float* __restrict__ out) {
  __shared__ __attribute__((aligned(16))) bf16 ldsW[128 * 64];
  __shared__ __attribute__((aligned(16))) bf16 ldsX[128 * 64];

  const int t = threadIdx.x;
  const int bid = blockIdx.x;
  const int combo = bid & 7;          // -> XCD (round-robin): B-panel stays L2-resident
  const int mtile = bid >> 3;
  const int py = combo >> 2, px = (combo >> 1) & 1, ntile = combo & 1;
  const int ph = py * 2 + px;
  const int oc0 = ntile * 128;
  const int m0 = mtile * 128;
  const int n_img = m0 >> 12;
  const int oy0 = (m0 & 4095) >> 6;   // even; tile covers oy0, oy0+1

  const int w = t >> 6, lane = t & 63;
  const int wr = w >> 1, wc = w & 1;  // 2x2 wave grid: wr = oc quad, wc = m quad
  const int lr = lane & 15, lg = lane >> 4;

  f32x4 acc[4][4];
#pragma unroll
  for (int i = 0; i < 4; ++i)
#pragma unroll
    for (int j = 0; j < 4; ++j) acc[i][j] = (f32x4){0.f, 0.f, 0.f, 0.f};

  for (int ks = 0; ks < 36; ++ks) {
    const int tap = ks >> 2, cb = ks & 3;
    const int jy = tap / 3, jx = tap - jy * 3;
    const int c0 = cb * 64;
    const size_t wtapbase = ((size_t)(ph * 9 + tap) * 256 + oc0) * 256 + c0;
    const size_t xbase = (((size_t)n_img * 66 + oy0 + jy) * 66 + jx) * 256 + c0;

    // ---- stage both tiles ([128 rows][64 k] bf16) via global_load_lds ----
#pragma unroll
    for (int r = 0; r < 4; ++r) {
      const int idx = r * 256 + t;
      const int row = idx >> 3;
      const int colb = (idx & 7) * 16;
      const int src = colb ^ ((row & 7) << 4);  // pre-swizzled source column
      const bf16* gw = wsub + wtapbase + (size_t)row * 256;
      const bf16* gx = xpad + xbase + ((size_t)(row >> 6) * 66 + (row & 63)) * 256;
      bf16* lw = ldsW + (size_t)(r * 256 + (t & 192)) * 8;  // wave-uniform base
      bf16* lx = ldsX + (size_t)(r * 256 + (t & 192)) * 8;
      __builtin_amdgcn_global_load_lds(AS1((const char*)gw + src), AS3(lw), 16, 0, 0);
      __builtin_amdgcn_global_load_lds(AS1((const char*)gx + src), AS3(lx), 16, 0, 0);
    }
    __syncthreads();

    // ---- compute: 2 k-substeps x 16 MFMAs per wave ----
#pragma unroll
    for (int kk = 0; kk < 2; ++kk) {
      bf16x8 af[4], bfr[4];
#pragma unroll
      for (int i = 0; i < 4; ++i) {
        const int row = wr * 64 + i * 16 + lr;
        const int off = row * 128 + ((kk * 64 + lg * 16) ^ ((row & 7) << 4));
        af[i] = *(const bf16x8*)((const char*)ldsW + off);
      }
#pragma unroll
      for (int j = 0; j < 4; ++j) {
        const int row = wc * 64 + j * 16 + lr;
        const int off = row * 128 + ((kk * 64 + lg * 16) ^ ((row & 7) << 4));
        bfr[j] = *(const bf16x8*)((const char*)ldsX + off);
      }
#pragma unroll
      for (int i = 0; i < 4; ++i)
#pragma unroll
        for (int j = 0; j < 4; ++j)
          acc[i][j] = __builtin_amdgcn_mfma_f32_16x16x32_bf16(af[i], bfr[j], acc[i][j], 0, 0, 0);
    }
    __syncthreads();
  }

  // ---- epilogue: C row = oc (lg*4+reg), col = m (lr); + bias ----
#pragma unroll
  for (int i = 0; i < 4; ++i) {
    const int ocb = oc0 + wr * 64 + i * 16 + lg * 4;
    const float4 bv = *(const float4*)&bias[ocb];
    const float bvals[4] = {bv.x, bv.y, bv.z, bv.w};
#pragma unroll
    for (int j = 0; j < 4; ++j) {
      const int mloc = wc * 64 + j * 16 + lr;
      const int s = 2 * (oy0 + (mloc >> 6)) + py;
      const int tc = 2 * (mloc & 63) + px;
#pragma unroll
      for (int reg = 0; reg < 4; ++reg) {
        const int oc = ocb + reg;
        out[(((size_t)n_img * 256 + oc) * 128 + s) * 128 + tc] = acc[i][j][reg] + bvals[reg];
      }
    }
  }
}

// ---------------------------------------------------------------------------
extern "C" void kernel_launch(void* const* d_in, const int* in_sizes, int n_in,
                              void* d_out, int out_size, void* d_ws, size_t ws_size,
                              hipStream_t stream) {
  const float* x = (const float*)d_in[0];
  const float* wgt = (const float*)d_in[1];
  const float* bias = (const float*)d_in[2];
  float* out = (float*)d_out;

  const size_t WSUB_BYTES = (size_t)4 * 9 * 256 * 256 * 2;          // 4.72 MB
  const size_t XPAD_BYTES = (size_t)16 * 66 * 66 * 256 * 2;         // 35.7 MB
  if (ws_size < WSUB_BYTES + XPAD_BYTES) return;  // workspace too small

  bf16* wsub = (bf16*)d_ws;
  bf16* xpad = (bf16*)((char*)d_ws + WSUB_BYTES);

  hipMemsetAsync(xpad, 0, XPAD_BYTES, stream);                       // zero padding
  prep_wsub_k<<<256, 256, 0, stream>>>(wgt, wsub);
  xpose_k<<<16 * 64 * 4, 256, 0, stream>>>(x, xpad);
  conv_k<<<4096, 256, 0, stream>>>(xpad, wsub, bias, out);
}